// Round 1
// baseline (260.727 us; speedup 1.0000x reference)
//
#include <hip/hip_runtime.h>
#include <stdint.h>
#include <math.h>

#define B_ 32
#define D_ 256
#define N_ 4096   // H*W
#define K_ 2048   // keep = N/2
#define PT 32     // gather tile: selected tokens per block

// ---------------- Kernel 1: fused transpose+LN+linear score --------------
// score[b,n] = rsqrt(var+eps) * (dot(t, wv) - mu*S1) + S2
// wv[d] = norm_w[d]*fc_w[d]; S1 = sum wv; S2 = sum norm_b*fc_w + fc_b
__global__ __launch_bounds__(256) void score_kernel(
    const float* __restrict__ tokens,
    const float* __restrict__ norm_w, const float* __restrict__ norm_b,
    const float* __restrict__ fc_w, const float* __restrict__ fc_b,
    double* __restrict__ scores)
{
    __shared__ float wv[D_];
    __shared__ double r1[256];
    __shared__ double r2[256];
    const int tid = threadIdx.x;
    const int b = blockIdx.y;
    const int n = blockIdx.x * 256 + tid;

    const float nw = norm_w[tid];
    const float fw = fc_w[tid];
    const float nb = norm_b[tid];
    wv[tid] = nw * fw;
    r1[tid] = (double)nw * (double)fw;
    r2[tid] = (double)nb * (double)fw;
    __syncthreads();
    for (int off = 128; off > 0; off >>= 1) {
        if (tid < off) { r1[tid] += r1[tid + off]; r2[tid] += r2[tid + off]; }
        __syncthreads();
    }
    const double S1 = r1[0];
    const double S2 = r2[0] + (double)fc_b[0];

    const float* tp = tokens + (size_t)b * D_ * N_ + n;
    double sum = 0.0, sumsq = 0.0, dot = 0.0;
#pragma unroll 8
    for (int d = 0; d < D_; ++d) {
        double v = (double)tp[(size_t)d * N_];   // coalesced across n
        sum += v;
        sumsq += v * v;
        dot += v * (double)wv[d];
    }
    const double mu = sum * (1.0 / D_);
    const double var = sumsq * (1.0 / D_) - mu * mu;
    const double sc = (dot - mu * S1) / sqrt(var + 1e-5) + S2;
    scores[(size_t)b * N_ + n] = sc;
}

// ---------------- Kernel 2: per-batch top-K select + compact --------------
// One block per batch. 256 threads x 16 keys each (contiguous chunks so the
// compaction comes out in ascending spatial order -> matches jnp.sort(idx)).
__global__ __launch_bounds__(256) void select_kernel(
    const double* __restrict__ scores, int* __restrict__ sel_idx)
{
    const int b = blockIdx.x;
    const int tid = threadIdx.x;
    __shared__ unsigned buf[256];
    __shared__ unsigned sh_scan[256];
    __shared__ unsigned long long sh_prefix;
    __shared__ int sh_k;

    unsigned long long key[16];
    const double* sp = scores + (size_t)b * N_;
    const int base = tid * 16;
#pragma unroll
    for (int i = 0; i < 16; ++i) {
        unsigned long long u = (unsigned long long)__double_as_longlong(sp[base + i]);
        // order-preserving map: larger double -> larger uint64
        u = (u & 0x8000000000000000ULL) ? ~u : (u | 0x8000000000000000ULL);
        key[i] = u;
    }

    unsigned long long prefix = 0ULL;
    int k = K_;  // rank remaining (1-indexed k-th largest)
    for (int pass = 0; pass < 8; ++pass) {
        const int shift = 56 - 8 * pass;
        buf[tid] = 0u;
        __syncthreads();
        const unsigned long long pmask = (pass == 0) ? 0ULL : (~0ULL << (shift + 8));
#pragma unroll
        for (int i = 0; i < 16; ++i) {
            if ((key[i] & pmask) == prefix)
                atomicAdd(&buf[(unsigned)((key[i] >> shift) & 255ULL)], 1u);
        }
        __syncthreads();
        // suffix sum over bins: buf[t] = sum_{j>=t} hist[j]
        for (int off = 1; off < 256; off <<= 1) {
            unsigned add = (tid + off < 256) ? buf[tid + off] : 0u;
            __syncthreads();
            buf[tid] += add;
            __syncthreads();
        }
        const unsigned s_here = buf[tid];
        const unsigned s_next = (tid < 255) ? buf[tid + 1] : 0u;
        if (s_here >= (unsigned)k && s_next < (unsigned)k) {  // unique bin
            sh_prefix = prefix | ((unsigned long long)tid << shift);
            sh_k = k - (int)s_next;
        }
        __syncthreads();
        prefix = sh_prefix;
        k = sh_k;
        __syncthreads();
    }
    const unsigned long long T = prefix;  // exact K-th largest key
    const int ties_needed = k;            // how many == T to take (lowest n first)

    // exclusive scan of per-thread equal-count (for tie ranks)
    int loc_eq = 0;
#pragma unroll
    for (int i = 0; i < 16; ++i) loc_eq += (key[i] == T);
    sh_scan[tid] = (unsigned)loc_eq;
    __syncthreads();
    for (int off = 1; off < 256; off <<= 1) {
        unsigned add = (tid >= off) ? sh_scan[tid - off] : 0u;
        __syncthreads();
        sh_scan[tid] += add;
        __syncthreads();
    }
    const int eq_before = (int)sh_scan[tid] - loc_eq;
    __syncthreads();

    // selection flags + compaction positions
    int sel[16];
    int loc_sel = 0;
    int eq_run = eq_before;
#pragma unroll
    for (int i = 0; i < 16; ++i) {
        int s;
        if (key[i] > T) s = 1;
        else if (key[i] == T) { s = (eq_run < ties_needed) ? 1 : 0; eq_run++; }
        else s = 0;
        sel[i] = s;
        loc_sel += s;
    }
    sh_scan[tid] = (unsigned)loc_sel;
    __syncthreads();
    for (int off = 1; off < 256; off <<= 1) {
        unsigned add = (tid >= off) ? sh_scan[tid - off] : 0u;
        __syncthreads();
        sh_scan[tid] += add;
        __syncthreads();
    }
    int pos = (int)sh_scan[tid] - loc_sel;
    int* op = sel_idx + (size_t)b * K_;
#pragma unroll
    for (int i = 0; i < 16; ++i) {
        if (sel[i]) op[pos++] = base + i;
    }
}

// ---------------- Kernel 3: gather with LDS transpose ---------------------
// out[b, p, d] = tokens[b, d, n_p]; reads strided over d, writes coalesced.
__global__ __launch_bounds__(256) void gather_kernel(
    const float* __restrict__ tokens, const int* __restrict__ sel_idx,
    float* __restrict__ out)
{
    __shared__ float tile[D_][PT + 1];  // +1 pad: conflict-free both phases
    __shared__ int nn[PT];
    const int b = blockIdx.y;
    const int p0 = blockIdx.x * PT;
    const int tid = threadIdx.x;

    if (tid < PT) nn[tid] = sel_idx[(size_t)b * K_ + p0 + tid];
    __syncthreads();

    // phase 1: load tokens[b][d][n_p] -> tile[d][p]
    const int p = tid & 31;
    const int dg = tid >> 5;  // 8 d-groups
    const float* tp = tokens + (size_t)b * D_ * N_;
    const int n = nn[p];
    for (int d = dg; d < D_; d += 8)
        tile[d][p] = tp[(size_t)d * N_ + n];
    __syncthreads();

    // phase 2: coalesced write out[b][p][d]
    const int lane = tid & 63;
    const int w = tid >> 6;  // 4 waves, 8 p-rows each
    float* op = out + ((size_t)b * K_ + p0) * D_;
    for (int pp = w * 8; pp < w * 8 + 8; ++pp)
        for (int dd = lane; dd < D_; dd += 64)
            op[(size_t)pp * D_ + dd] = tile[dd][pp];
}

extern "C" void kernel_launch(void* const* d_in, const int* in_sizes, int n_in,
                              void* d_out, int out_size, void* d_ws, size_t ws_size,
                              hipStream_t stream)
{
    const float* tokens = (const float*)d_in[0];
    const float* norm_w = (const float*)d_in[1];
    const float* norm_b = (const float*)d_in[2];
    const float* fc_w   = (const float*)d_in[3];
    const float* fc_b   = (const float*)d_in[4];
    float* out = (float*)d_out;

    double* scores = (double*)d_ws;                                  // 1 MB
    int* sel_idx = (int*)((char*)d_ws + (size_t)B_ * N_ * sizeof(double)); // 256 KB

    score_kernel<<<dim3(N_ / 256, B_), 256, 0, stream>>>(
        tokens, norm_w, norm_b, fc_w, fc_b, scores);
    select_kernel<<<dim3(B_), 256, 0, stream>>>(scores, sel_idx);
    gather_kernel<<<dim3(K_ / PT, B_), 256, 0, stream>>>(tokens, sel_idx, out);
}